// Round 6
// baseline (122.210 us; speedup 1.0000x reference)
//
#include <hip/hip_runtime.h>
#include <hip/hip_fp16.h>

#define VOC    512
#define EMB    128
#define L_SEQ  32
#define NWORDS 16384
#define NCOL   416
#define WPB    128         // words per conv block
#define SUBW   32          // subtable row width (halves)
#define SUBSTRIDE_H 16416  // 513*32 halves per subtable
#define SCP    40          // sc row pitch in u16 (80 B)

// pe: 13 subtables of 513 rows x 32 halves (row VOC=512 all-zero).
//   seg0 (k2): sub 0, QUAD-interleaved: loc = (ol>>2)*8 + j*4 + (ol&3)
//   seg1 (k3): sub 1+(ol>>3), loc = ((ol&7)>>1)*8 + j*2 + (ol&1)  (pairs)
//   seg2 (k4): sub 3+(ol>>3), same formula
//   seg3 (k5): sub 5+(ol>>2), loc = (ol&3)*8 + j   (filter-major)
//   seg4 (k6): sub 9+(ol>>2), loc = (ol&3)*8 + j

// -------- Kernel 1: fused pack+build, 2 chars per block ------------------
__global__ __launch_bounds__(512) void build_pe(
    const float* __restrict__ emb,
    const float* __restrict__ w2, const float* __restrict__ w3,
    const float* __restrict__ w4, const float* __restrict__ w5,
    const float* __restrict__ w6,
    __half* __restrict__ pe)
{
    __shared__ float e[2][EMB];
    const int tid = threadIdx.x;
    const int c0  = blockIdx.x * 2;
    if (tid < 2 * EMB) {
        const int ch = tid >> 7, i = tid & 127, c = c0 + ch;
        e[ch][i] = (c < VOC) ? emb[c * EMB + i] : 0.f;   // c>=VOC -> zero row
    }
    __syncthreads();
    const int col = tid;
    if (col >= NCOL) return;

    int k, jpad, base, seg; const float* w;
    if (col < 32)       { k = 2; jpad = 2; base = 0;   seg = 0; w = w2; }
    else if (col < 96)  { k = 3; jpad = 4; base = 32;  seg = 1; w = w3; }
    else if (col < 160) { k = 4; jpad = 4; base = 96;  seg = 2; w = w4; }
    else if (col < 288) { k = 5; jpad = 8; base = 160; seg = 3; w = w5; }
    else                { k = 6; jpad = 8; base = 288; seg = 4; w = w6; }

    const int r  = col - base;
    const int ol = (jpad == 2) ? (r >> 1) : (jpad == 4) ? (r >> 2) : (r >> 3);
    const int j  = r & (jpad - 1);

    int sub, loc;
    if (seg == 0)      { sub = 0;           loc = (ol >> 2) * 8 + j * 4 + (ol & 3); }
    else if (seg == 1) { sub = 1 + (ol>>3); loc = ((ol & 7) >> 1) * 8 + j * 2 + (ol & 1); }
    else if (seg == 2) { sub = 3 + (ol>>3); loc = ((ol & 7) >> 1) * 8 + j * 2 + (ol & 1); }
    else if (seg == 3) { sub = 5 + (ol>>2); loc = (ol & 3) * 8 + j; }
    else               { sub = 9 + (ol>>2); loc = (ol & 3) * 8 + j; }

    float a0 = 0.f, a1 = 0.f;
    if (j < k) {                            // padded taps stay zero
        const float* wp = w + (ol * EMB) * k + j;
        #pragma unroll 8
        for (int i = 0; i < EMB; ++i) {
            const float wv = wp[i * k];     // w[(ol*EMB+i)*k + j]
            a0 += wv * e[0][i]; a1 += wv * e[1][i];
        }
    }
    const int bb = sub * SUBSTRIDE_H + loc;
    pe[bb + c0 * SUBW] = __float2half(a0);
    if (c0 + 1 <= VOC) pe[bb + (c0 + 1) * SUBW] = __float2half(a1);
}

// -------- Kernel 2: sub-split blocks, heavy-first, XCD-co-located --------
__device__ __forceinline__ float2 h2tof2(int u) {
    return __half22float2(__builtin_bit_cast(__half2, u));
}

__device__ __forceinline__ void sc_load(const unsigned short* __restrict__ sc,
                                        int w, int* __restrict__ d)
{
    const int4* sp = (const int4*)(sc + w * SCP);   // 80B pitch, 16B aligned
    #pragma unroll
    for (int g = 0; g < 4; ++g) {
        const int4 s4 = sp[g];
        d[4*g] = s4.x; d[4*g+1] = s4.y; d[4*g+2] = s4.z; d[4*g+3] = s4.w;
    }
}

// seg0 (k=2, PAD=0): 4 filters per lane via quad-interleaved b128 reads.
// 2-slot ring, bias folded into slot init: value = ((bias+v_j0)+v_j1),
// identical rounding order to the flat bias-init version.
__device__ __forceinline__ void convQ2(const char* __restrict__ tbl,
                                       const unsigned short* __restrict__ sc,
                                       int w, float2 ba, float2 bb,
                                       float2* __restrict__ mA,
                                       float2* __restrict__ mB)
{
    int d[16];
    sc_load(sc, w, d);
    float2 rA[2], rB[2];
    float2 xA = make_float2(-3.0e38f, -3.0e38f), xB = xA;

    #pragma unroll
    for (int tp = 0; tp < 32; ++tp) {
        const int dw = d[tp >> 1];
        const int pm = (tp & 1) ? (int)(((unsigned)dw) >> 16) : (dw & 0xffff);
        const int4 qq = *(const int4*)(tbl + pm);
        const int cur = tp & 1, prv = cur ^ 1;
        if (tp < 31) {                       // init output t = tp (j=0 taps)
            const float2 v0 = h2tof2(qq.x), v1 = h2tof2(qq.y);
            rA[cur] = make_float2(ba.x + v0.x, ba.y + v0.y);
            rB[cur] = make_float2(bb.x + v1.x, bb.y + v1.y);
        }
        if (tp > 0) {                        // j=1 taps complete t = tp-1
            const float2 u0 = h2tof2(qq.z), u1 = h2tof2(qq.w);
            rA[prv].x += u0.x; rA[prv].y += u0.y;
            rB[prv].x += u1.x; rB[prv].y += u1.y;
            xA.x = fmaxf(xA.x, rA[prv].x); xA.y = fmaxf(xA.y, rA[prv].y);
            xB.x = fmaxf(xB.x, rB[prv].x); xB.y = fmaxf(xB.y, rB[prv].y);
        }
    }
    *mA = xA; *mB = xB;
}

// Paired conv (segs 1-2): flat bias-initialized float2 accumulators.
template<int K, int PAD>
__device__ __forceinline__ float2 convP(const char* __restrict__ tbl,
                                        const unsigned short* __restrict__ sc,
                                        int w, float2 bias)
{
    constexpr int LOUT = L_SEQ + 2 * PAD - K + 1;
    int d[16];
    sc_load(sc, w, d);
    float2 s[LOUT];
    #pragma unroll
    for (int t = 0; t < LOUT; ++t) s[t] = bias;

    #pragma unroll
    for (int tp = 0; tp < 32; ++tp) {
        const int dw = d[tp >> 1];
        const int pm = (tp & 1) ? (int)(((unsigned)dw) >> 16) : (dw & 0xffff);
        const int4 qq = *(const int4*)(tbl + pm);
        const int W4[4] = {qq.x, qq.y, qq.z, qq.w};
        #pragma unroll
        for (int j = 0; j < K; ++j) {                   // K<=4 here
            const int t = tp + PAD - j;
            if (t >= 0 && t < LOUT) {
                const float2 v = h2tof2(W4[j]);
                s[t].x += v.x; s[t].y += v.y;
            }
        }
    }
    float2 m = s[0];
    #pragma unroll
    for (int t = 1; t < LOUT; ++t) {
        m.x = fmaxf(m.x, s[t].x); m.y = fmaxf(m.y, s[t].y);
    }
    return m;
}

// Scalar conv (segs 3-4): one filter, flat bias-initialized accumulators.
template<int K, int PAD>
__device__ __forceinline__ float convS(const char* __restrict__ tbl,
                                       const unsigned short* __restrict__ sc,
                                       int w, float bias)
{
    constexpr int LOUT = L_SEQ + 2 * PAD - K + 1;
    int d[16];
    sc_load(sc, w, d);
    float s[LOUT];
    #pragma unroll
    for (int t = 0; t < LOUT; ++t) s[t] = bias;

    #pragma unroll
    for (int tp = 0; tp < 32; ++tp) {
        const int dw = d[tp >> 1];
        const int pm = (tp & 1) ? (int)(((unsigned)dw) >> 16) : (dw & 0xffff);
        const int4 qq = *(const int4*)(tbl + pm);
        float v[K];
        {
            const float2 f0 = h2tof2(qq.x), f1 = h2tof2(qq.y), f2 = h2tof2(qq.z);
            v[0] = f0.x; v[1] = f0.y; v[2] = f1.x; v[3] = f1.y; v[4] = f2.x;
            if constexpr (K >= 6) v[5] = f2.y;
        }
        #pragma unroll
        for (int j = 0; j < K; ++j) {
            const int t = tp + PAD - j;
            if (t >= 0 && t < LOUT) s[t] += v[j];
        }
    }
    float m = s[0];
    #pragma unroll
    for (int t = 1; t < LOUT; ++t) m = fmaxf(m, s[t]);
    return m;
}

// Pack 8 chars (2 x int4) into one 16B LDS write of pre-multiplied u16s.
__device__ __forceinline__ void sc_write(unsigned short* __restrict__ sc16,
                                         int tid, int4 a, int4 b)
{
    #define ENC(c) ((unsigned)((((c) >= 0) ? (c) : VOC) * 80))
    int4 o;
    o.x = (int)(ENC(a.x) | (ENC(a.y) << 16));
    o.y = (int)(ENC(a.z) | (ENC(a.w) << 16));
    o.z = (int)(ENC(b.x) | (ENC(b.y) << 16));
    o.w = (int)(ENC(b.z) | (ENC(b.w) << 16));
    #undef ENC
    *(int4*)(sc16 + (tid >> 2) * SCP + (tid & 3) * 8) = o;
}

__global__ __launch_bounds__(512, 4) void conv_max(
    const int*    __restrict__ word,
    const __half* __restrict__ pe,
    const float* __restrict__ b2, const float* __restrict__ b3,
    const float* __restrict__ b4, const float* __restrict__ b5,
    const float* __restrict__ b6,
    float*       __restrict__ out)
{
    // 41,040 B table (513 x 80 B pitch) + 10,240 B sc = 51,280 B -> 3/CU
    __shared__ __align__(16) __half tab[513 * 40];
    __shared__ __align__(16) unsigned short sc16[WPB * SCP];

    const int tid = threadIdx.x;
    const int wb  = blockIdx.x & 127;        // word group; XCD = wb%8 (128%8==0)
    const int sub = 12 - (blockIdx.x >> 7);  // heavy subs (k6,k5) dispatch FIRST

    // stage subtable: 64B global rows -> 80B LDS pitch (bank-spread)
    {
        const int4* src = (const int4*)(pe + sub * SUBSTRIDE_H);
        char* tw = (char*)tab;
        for (int i = tid; i < 513 * 4; i += 512)
            *(int4*)(tw + (i >> 2) * 80 + (i & 3) * 16) = src[i];
    }
    // stage word offsets (vectorized: 2 int4 loads -> 1 b128 write)
    {
        const int4* wp4 = (const int4*)(word + wb * (WPB * L_SEQ)) + tid * 2;
        sc_write(sc16, tid, wp4[0], wp4[1]);
    }
    __syncthreads();

    const char* tb = (const char*)tab;
    float* ob = out + wb * (WPB * 80);
    const int q = tid & 3, w = tid >> 2;     // 4 lanes per word, ALL subs

    if (sub == 0) {
        // seg0: 4 filters/lane (quad-interleaved), 128 words, b128 taps
        const char* tbl = tb + q * 16;
        const float2 ba = {b2[4*q],     b2[4*q + 1]};
        const float2 bb = {b2[4*q + 2], b2[4*q + 3]};
        float2 mA, mB;
        convQ2(tbl, sc16, w, ba, bb, &mA, &mB);
        float4 o4; o4.x = mA.x; o4.y = mA.y; o4.z = mB.x; o4.w = mB.y;
        *(float4*)(ob + w * 80 + 4*q) = o4;
    } else if (sub <= 4) {
        // segs 1-2: 4 filter-pairs x 128 words, b128 taps
        const char* tbl = tb + q * 16;
        const int half = (sub - 1) & 1;
        const bool is1 = (sub <= 2);
        const float* bp = is1 ? b3 : b4;
        const int f0 = half * 8 + 2 * q;
        const float2 bias = {bp[f0], bp[f0 + 1]};
        const int oo = (is1 ? 16 : 32) + f0;
        float2 m;
        if (is1) m = convP<3, 0>(tbl, sc16, w, bias);
        else     m = convP<4, 1>(tbl, sc16, w, bias);
        *(float2*)(ob + w * 80 + oo) = m;
    } else if (sub <= 8) {
        // seg3 (k5): 4 filters x 128 words
        const char* tbl = tb + q * 16;
        const int f = (sub - 5) * 4 + q;
        const float m = convS<5, 2>(tbl, sc16, w, b5[f]);
        ob[w * 80 + 48 + f] = m;
    } else {
        // seg4 (k6): 4 filters x 128 words
        const char* tbl = tb + q * 16;
        const int f = (sub - 9) * 4 + q;
        const float m = convS<6, 3>(tbl, sc16, w, b6[f]);
        ob[w * 80 + 64 + f] = m;
    }
}

extern "C" void kernel_launch(void* const* d_in, const int* in_sizes, int n_in,
                              void* d_out, int out_size, void* d_ws, size_t ws_size,
                              hipStream_t stream)
{
    const int*   word = (const int*)  d_in[0];
    const float* emb  = (const float*)d_in[1];
    const float* w2   = (const float*)d_in[2];
    const float* b2   = (const float*)d_in[3];
    const float* w3   = (const float*)d_in[4];
    const float* b3   = (const float*)d_in[5];
    const float* w4   = (const float*)d_in[6];
    const float* b4   = (const float*)d_in[7];
    const float* w5   = (const float*)d_in[8];
    const float* b5   = (const float*)d_in[9];
    const float* w6   = (const float*)d_in[10];
    const float* b6   = (const float*)d_in[11];
    float* out = (float*)d_out;

    __half* pe16 = (__half*)d_ws;   // 13 * 16416 halves = 426,816 B

    build_pe<<<257, 512, 0, stream>>>(emb, w2, w3, w4, w5, w6, pe16);

    conv_max<<<13 * 128, 512, 0, stream>>>(
        word, pe16, b2, b3, b4, b5, b6, out);
}

// Round 7
// 105.503 us; speedup vs baseline: 1.1584x; 1.1584x over previous
//
#include <hip/hip_runtime.h>
#include <hip/hip_fp16.h>

#define VOC    512
#define EMB    128
#define L_SEQ  32
#define NWORDS 16384
#define NCOL   416
#define WPB    128      // words per conv block
#define SCP    48       // sc row pitch in u16 (96 B, 16B-aligned, <=2-way banks)

// Half-split subtables: sub = seg*2 + half (8 filters each).
// Widths in halves: seg0:16, seg1/2:32, seg3/4:64. Row VOC (512) is all-zero.
__device__ __constant__ int SUBBASE[10] = {0, 8208, 16416, 32832, 49248,
                                           65664, 82080, 114912, 147744, 180576};
__device__ __constant__ int SUBW[10]    = {16, 16, 32, 32, 32, 32, 64, 64, 64, 64};

// -------- Kernel 1: fused pack+build, 2 chars per block --------
__global__ __launch_bounds__(512) void build_pe(
    const float* __restrict__ emb,
    const float* __restrict__ w2, const float* __restrict__ w3,
    const float* __restrict__ w4, const float* __restrict__ w5,
    const float* __restrict__ w6,
    __half* __restrict__ pe)
{
    __shared__ float e[2][EMB];
    const int tid = threadIdx.x;
    const int c0  = blockIdx.x * 2;
    if (tid < 2 * EMB) {
        const int ch = tid >> 7, i = tid & 127, c = c0 + ch;
        e[ch][i] = (c < VOC) ? emb[c * EMB + i] : 0.f;   // c>=VOC -> zero row
    }
    __syncthreads();
    const int col = tid;
    if (col >= NCOL) return;

    int k, jpad, base, seg; const float* w;
    if (col < 32)       { k = 2; jpad = 2; base = 0;   seg = 0; w = w2; }
    else if (col < 96)  { k = 3; jpad = 4; base = 32;  seg = 1; w = w3; }
    else if (col < 160) { k = 4; jpad = 4; base = 96;  seg = 2; w = w4; }
    else if (col < 288) { k = 5; jpad = 8; base = 160; seg = 3; w = w5; }
    else                { k = 6; jpad = 8; base = 288; seg = 4; w = w6; }

    const int r  = col - base;
    const int ol = (jpad == 2) ? (r >> 1) : (jpad == 4) ? (r >> 2) : (r >> 3);
    const int j  = r & (jpad - 1);

    const int sub = seg * 2 + ((jpad == 2) ? (ol >> 3)
                    : (seg <= 2) ? (ol >> 3) : (ol >> 3));
    int loc;
    if (seg == 0)      loc = (ol & 7) * 2 + j;
    else if (seg <= 2) loc = (ol & 7) * 4 + j;
    else               loc = (ol & 7) * 8 + j;

    float a0 = 0.f, a1 = 0.f;
    if (j < k) {                            // padded taps stay zero
        const float* wp = w + (ol * EMB) * k + j;
        #pragma unroll 8
        for (int i = 0; i < EMB; ++i) {
            const float wv = wp[i * k];     // w[(ol*EMB+i)*k + j]
            a0 += wv * e[0][i]; a1 += wv * e[1][i];
        }
    }
    const int W = SUBW[sub], Bb = SUBBASE[sub];
    pe[Bb + c0 * W + loc] = __float2half(a0);
    if (c0 + 1 <= VOC) pe[Bb + (c0 + 1) * W + loc] = __float2half(a1);
}

// -------- Kernel 2: LDS-resident half-table conv + max --------
__device__ __forceinline__ float2 h2tof2(int u) {
    return __half22float2(__builtin_bit_cast(__half2, u));
}

template<int K> struct LdT;
template<> struct LdT<2> { using T = int;  };
template<> struct LdT<3> { using T = int2; };
template<> struct LdT<4> { using T = int2; };
template<> struct LdT<5> { using T = int4; };
template<> struct LdT<6> { using T = int4; };

template<int K>
__device__ __forceinline__ void unpack(typename LdT<K>::T q, float* v) {
    if constexpr (K == 2) {
        float2 f = h2tof2(q); v[0] = f.x; v[1] = f.y;
    } else if constexpr (K == 3) {
        float2 f0 = h2tof2(q.x), f1 = h2tof2(q.y);
        v[0] = f0.x; v[1] = f0.y; v[2] = f1.x;
    } else if constexpr (K == 4) {
        float2 f0 = h2tof2(q.x), f1 = h2tof2(q.y);
        v[0] = f0.x; v[1] = f0.y; v[2] = f1.x; v[3] = f1.y;
    } else if constexpr (K == 5) {
        float2 f0 = h2tof2(q.x), f1 = h2tof2(q.y), f2 = h2tof2(q.z);
        v[0] = f0.x; v[1] = f0.y; v[2] = f1.x; v[3] = f1.y; v[4] = f2.x;
    } else {
        float2 f0 = h2tof2(q.x), f1 = h2tof2(q.y), f2 = h2tof2(q.z);
        v[0] = f0.x; v[1] = f0.y; v[2] = f1.x; v[3] = f1.y;
        v[4] = f2.x; v[5] = f2.y;
    }
}

// sc: row-major [word][SCP] u16 pre-multiplied (c*rowBytes)>>1.
// 4 x ds_read_b128 pulls all 32 tap offsets into registers up front;
// per-tap address = (extract u16 << 1) + lb  (register-only, no DS).
template<int K, int PAD, int LANEB>
__device__ __forceinline__ float convseg(
    const char* __restrict__ tb, const unsigned short* __restrict__ sc,
    int w, int lb, float bias)
{
    using LT = typename LdT<K>::T;
    constexpr int LOUT = L_SEQ + 2 * PAD - K + 1;

    int4 s4[4];
    {
        const int4* sp = (const int4*)(sc + w * SCP);   // 96B pitch, 16B aligned
        #pragma unroll
        for (int g = 0; g < 4; ++g) s4[g] = sp[g];
    }

    float s[LOUT];
    #pragma unroll
    for (int t = 0; t < LOUT; ++t) s[t] = bias;

    #pragma unroll
    for (int g = 0; g < 4; ++g) {
        const int dd[4] = {s4[g].x, s4[g].y, s4[g].z, s4[g].w};
        LT q[8];
        #pragma unroll
        for (int u = 0; u < 8; ++u) {
            const int pm = (u & 1) ? (int)(((unsigned)dd[u >> 1]) >> 16)
                                   : (dd[u >> 1] & 0xffff);
            q[u] = *(const LT*)(tb + (pm << 1) + lb);
        }
        #pragma unroll
        for (int u = 0; u < 8; ++u) {
            const int tp = g * 8 + u;
            float v[K];
            unpack<K>(q[u], v);
            #pragma unroll
            for (int j = 0; j < K; ++j) {
                const int t = tp + PAD - j;
                if (t >= 0 && t < LOUT) s[t] += v[j];
            }
        }
    }

    float m = s[0];
    #pragma unroll
    for (int t = 1; t < LOUT; ++t) m = fmaxf(m, s[t]);
    return m;
}

// Pack 8 chars (2 x int4) into one 16B LDS write of pre-shifted u16 offsets.
// For i = tid*8+u: row i>>5 == tid>>2, col i&31 == (tid&3)*8+u (contiguous).
__device__ __forceinline__ void sc_write(unsigned short* __restrict__ sc16,
                                         int tid, int4 a, int4 b, int shb)
{
    #define ENC(c) ((unsigned)((((c) >= 0) ? (c) : VOC) << shb))
    int4 o;
    o.x = (int)(ENC(a.x) | (ENC(a.y) << 16));
    o.y = (int)(ENC(a.z) | (ENC(a.w) << 16));
    o.z = (int)(ENC(b.x) | (ENC(b.y) << 16));
    o.w = (int)(ENC(b.z) | (ENC(b.w) << 16));
    #undef ENC
    *(int4*)(sc16 + (tid >> 2) * SCP + (tid & 3) * 8) = o;
}

__global__ __launch_bounds__(512, 4) void conv_max(
    const int*    __restrict__ word,
    const __half* __restrict__ pe,
    const float* __restrict__ b2, const float* __restrict__ b3,
    const float* __restrict__ b4, const float* __restrict__ b5,
    const float* __restrict__ b6,
    float*       __restrict__ out)
{
    // 65,664 B half-table + 12,288 B sc = 77,952 B -> 2 blocks/CU (160 KiB)
    __shared__ __align__(16) __half tab[513 * 64];
    __shared__ __align__(16) unsigned short sc16[WPB * SCP];

    const int tid  = threadIdx.x;
    const int sub  = blockIdx.x % 10;     // block-uniform (seg, filter-half)
    const int wb   = blockIdx.x / 10;
    const int seg  = sub >> 1;
    const int half = sub & 1;

    // stage half-subtable: contiguous, coalesced, L2-resident
    const int  W16 = SUBW[sub];
    const int  nI4 = (513 * W16) >> 3;
    const int4* src = (const int4*)(pe + SUBBASE[sub]);
    int4* dst = (int4*)tab;
    for (int i = tid; i < nI4; i += 512) dst[i] = src[i];

    // stage pre-shifted char offsets, vectorized (2 int4 loads -> 1 b128 write)
    {
        const int shb = (seg == 0) ? 4 : (seg <= 2) ? 5 : 6;   // log2(rowB/2)
        const int4* wp4 = (const int4*)(word + wb * (WPB * L_SEQ)) + tid * 2;
        sc_write(sc16, tid, wp4[0], wp4[1], shb);
    }
    __syncthreads();

    const int ol = tid & 7;               // filter within half
    const int w0 = tid >> 3;              // word 0..63; second word +64
    const float* bp = (seg == 0) ? b2 : (seg == 1) ? b3 :
                      (seg == 2) ? b4 : (seg == 3) ? b5 : b6;
    const float bias = bp[half * 8 + ol];
    const char* tb = (const char*)tab;

    float m0, m1;
    switch (seg) {
        case 0:  m0 = convseg<2, 0, 4 >(tb, sc16, w0,      ol * 4,  bias);
                 m1 = convseg<2, 0, 4 >(tb, sc16, w0 + 64, ol * 4,  bias); break;
        case 1:  m0 = convseg<3, 0, 8 >(tb, sc16, w0,      ol * 8,  bias);
                 m1 = convseg<3, 0, 8 >(tb, sc16, w0 + 64, ol * 8,  bias); break;
        case 2:  m0 = convseg<4, 1, 8 >(tb, sc16, w0,      ol * 8,  bias);
                 m1 = convseg<4, 1, 8 >(tb, sc16, w0 + 64, ol * 8,  bias); break;
        case 3:  m0 = convseg<5, 2, 16>(tb, sc16, w0,      ol * 16, bias);
                 m1 = convseg<5, 2, 16>(tb, sc16, w0 + 64, ol * 16, bias); break;
        default: m0 = convseg<6, 3, 16>(tb, sc16, w0,      ol * 16, bias);
                 m1 = convseg<6, 3, 16>(tb, sc16, w0 + 64, ol * 16, bias); break;
    }
    const int oc = seg * 16 + half * 8 + ol;
    out[(wb * WPB + w0     ) * 80 + oc] = m0;
    out[(wb * WPB + w0 + 64) * 80 + oc] = m1;
}

extern "C" void kernel_launch(void* const* d_in, const int* in_sizes, int n_in,
                              void* d_out, int out_size, void* d_ws, size_t ws_size,
                              hipStream_t stream)
{
    const int*   word = (const int*)  d_in[0];
    const float* emb  = (const float*)d_in[1];
    const float* w2   = (const float*)d_in[2];
    const float* b2   = (const float*)d_in[3];
    const float* w3   = (const float*)d_in[4];
    const float* b3   = (const float*)d_in[5];
    const float* w4   = (const float*)d_in[6];
    const float* b4   = (const float*)d_in[7];
    const float* w5   = (const float*)d_in[8];
    const float* b5   = (const float*)d_in[9];
    const float* w6   = (const float*)d_in[10];
    const float* b6   = (const float*)d_in[11];
    float* out = (float*)d_out;

    __half* pe16 = (__half*)d_ws;   // 426,816 B

    build_pe<<<257, 512, 0, stream>>>(emb, w2, w3, w4, w5, w6, pe16);

    conv_max<<<10 * (NWORDS / WPB), 512, 0, stream>>>(
        word, pe16, b2, b3, b4, b5, b6, out);
}